// Round 14
// baseline (88.140 us; speedup 1.0000x reference)
//
#include <hip/hip_runtime.h>

// GridSamplePScan: out[b,t,c] = sum_{k<=t} bilinear(images[b,k,c], wrap(base + cum_t - cum_k))
// B=4, L=32, C=16, H=W=64, fp32 in/out.
//
// R13 = R12 (63.1us, proven) + cross-iteration software pipeline:
//   R12 iter = coords(VALU) -> gathers(LDS) -> MACs(VALU) serialized by data
//   dependence, all waves in lockstep -> pipes SUM (4590cy = 1930V + 2550L).
//   Coords for iter i+1 depend only on cum (global, prefetched), NOT on the
//   staged frame -> precompute them during iter i's gather window:
//     barrier -> issue gathers(i) [addrs ready] -> STAGE(i+1) ->
//     coords(i+1) VALU under ds_read latency -> MACs(i)
//   ck loads prefetched 2 iters ahead; ct rows for both phases preloaded.
//   Math bit-identical to R12 (absmax 0.0625).

constexpr int BN = 4, LN = 32, CN = 16, HWn = 4096;
constexpr int FRAME = CN * HWn;
constexpr int PW = 66, PCELLS = PW * PW;                       // 4356 cells
constexpr int CHUNK_B = PCELLS * 16;                           // 69696 B
constexpr size_t TIMG_BYTES = (size_t)BN * LN * 2 * CHUNK_B;   // ~17.8 MB
constexpr size_t CUM_BYTES  = (size_t)BN * LN * HWn * 2 * 4;   // 4 MB

// ---------------------------------------------------------------------------
// images fp32 [B,L,C,H,W] -> fp16 padded [B*L][chh(2)][66][66][8ch] 16B cells.
// ---------------------------------------------------------------------------
__global__ __launch_bounds__(1024) void prep_pad(
        const float* __restrict__ img, float4* __restrict__ timg) {
    const int f = blockIdx.x >> 1, g = blockIdx.x & 1;         // frame, chhalf
    const float* src = img + (size_t)f * FRAME + g * (8 * HWn);
    float4* dst = timg + (size_t)blockIdx.x * PCELLS;
    for (int q = threadIdx.x; q < PCELLS; q += 1024) {
        const int y = q / PW, x = q - y * PW;
        union { float4 f4; _Float16 h[8]; } cell;
        if (y >= 1 && y <= 64 && x >= 1 && x <= 64) {
            const int p = ((y - 1) << 6) + (x - 1);
#pragma unroll
            for (int c = 0; c < 8; ++c)
                cell.h[c] = (_Float16)src[c * HWn + p];        // coalesced
        } else {
            cell.f4 = make_float4(0.f, 0.f, 0.f, 0.f);         // zero pad
        }
        dst[q] = cell.f4;
    }
}

// ---------------------------------------------------------------------------
// cumsum(flows) * 0.5 (exact scaling of the ROUNDED cumsum) -> [B*L][4096]
// ---------------------------------------------------------------------------
__global__ __launch_bounds__(256) void prep_cum(
        const float* __restrict__ flows, float2* __restrict__ cum) {
    const int b = blockIdx.x >> 4;
    const int p = ((blockIdx.x & 15) << 8) + threadIdx.x;
    const float* fl = flows + (size_t)b * (LN * 2 * HWn) + p;
    float cx = 0.f, cy = 0.f;
    for (int l = 0; l < LN; ++l) {              // ascending == jnp.cumsum
        cx += fl[(2 * l) * HWn];
        cy += fl[(2 * l + 1) * HWn];
        cum[(size_t)(b * LN + l) * HWn + p] =
            make_float2(cx * 0.5f, cy * 0.5f);  // exact *0.5
    }
}

// ---------------------------------------------------------------------------
// Guaranteed v_fma_mix_f32: acc += (float)f16(lo/hi of g) * w  (f32 fma)
// ---------------------------------------------------------------------------
__device__ __forceinline__ void mix_lo(float& acc, unsigned g, float w) {
    asm("v_fma_mix_f32 %0, %1, %2, %0 op_sel_hi:[1,0,0]"
        : "+v"(acc) : "v"(g), "v"(w));
}
__device__ __forceinline__ void mix_hi(float& acc, unsigned g, float w) {
    asm("v_fma_mix_f32 %0, %1, %2, %0 op_sel:[1,0,0] op_sel_hi:[1,0,0]"
        : "+v"(acc) : "v"(g), "v"(w));
}
__device__ __forceinline__ void mac8(float* __restrict__ acc, uint4 g, float w) {
    mix_lo(acc[0], g.x, w); mix_hi(acc[1], g.x, w);
    mix_lo(acc[2], g.y, w); mix_hi(acc[3], g.y, w);
    mix_lo(acc[4], g.z, w); mix_hi(acc[5], g.z, w);
    mix_lo(acc[6], g.w, w); mix_hi(acc[7], g.w, w);
}

// ---------------------------------------------------------------------------
// Coordinate/weight precompute (VALU only; no LDS dependence).
// ux = (bxh + dh) + 0.5 : reference association, halved (R12 proof).
// ---------------------------------------------------------------------------
struct PxCoord { int off; float w00, w10, w01, w11; };

__device__ __forceinline__ PxCoord px_coord(float2 ct, float2 ck,
                                            float bxh, float byh) {
    PxCoord r;
    const float ux = (bxh + (ct.x - ck.x)) + 0.5f;  // ref add order, halved
    const float uy = (byh + (ct.y - ck.y)) + 0.5f;
    const float fx = ux - floorf(ux);               // [0,1)
    const float fy = uy - floorf(uy);
    const float ixp = fmaf(fx, 64.0f, 0.5f);        // [0.5, 64.5)
    const float iyp = fmaf(fy, 64.0f, 0.5f);
    const float xf = floorf(ixp), yf = floorf(iyp);
    const float wx1 = ixp - xf, wy1 = iyp - yf;
    const float wx0 = 1.0f - wx1, wy0 = 1.0f - wy1;
    r.w00 = wx0 * wy0; r.w10 = wx1 * wy0;
    r.w01 = wx0 * wy1; r.w11 = wx1 * wy1;
    r.off = (int)yf * PW + (int)xf;                 // cell index, [0,64]^2
    return r;
}

// ---------------------------------------------------------------------------
// 256 blocks x 1024 thr (1/CU). Block = (b, pxhalf, pair, chh); thread: 2 px,
// 8 ch, 2 t-phases (triangle-paired: 33 uniform k-iters). R7 schedule +
// cross-iter coord pipeline.
// ---------------------------------------------------------------------------
__global__ __launch_bounds__(1024, 4) void gsps_lds(
        const float2* __restrict__ cum,
        const char* __restrict__ timg,
        float* __restrict__ out) {
    extern __shared__ char smem[];              // 2 x 69696 B double buffer
    const int bid = blockIdx.x;                 // 256 blocks
    const int xs  = bid & 7;                    // XCD slot
    const int b   = xs >> 1;                    // batch pinned to XCD pair
    const int pxh = xs & 1;
    const int seq = bid >> 3;
    const int pair = seq & 15;
    const int chh  = seq >> 4;
    const int tid  = threadIdx.x;
    const int t1 = 31 - pair;                   // heavy phase t  (>=16)
    const int t2 = pair;                        // light phase t

    const int px0 = (pxh << 11) + tid;
    const int px1 = px0 + 1024;
    // bxh = base_x/2 = (w+0.5)*2^-6 - 0.5   (both terms exact, diff exact)
    const float bx0 = ((float)(px0 & 63) + 0.5f) * 0.015625f - 0.5f;
    const float by0 = ((float)(px0 >> 6) + 0.5f) * 0.015625f - 0.5f;
    const float bx1 = ((float)(px1 & 63) + 0.5f) * 0.015625f - 0.5f;
    const float by1 = ((float)(px1 >> 6) + 0.5f) * 0.015625f - 0.5f;

    const float2* cb = cum + (size_t)b * (LN * HWn);
    const size_t chunk0 = ((size_t)b * LN * 2 + chh) * CHUNK_B;
    const unsigned wbase = (unsigned)(tid & ~63) << 4;   // wave-uniform

#define STAGE(KK, BUF) do {                                                   \
    const char* gsrc = timg + chunk0 + (size_t)(KK) * (2 * CHUNK_B);          \
    char* lbase = smem + (BUF) * CHUNK_B + wbase;                             \
    _Pragma("unroll")                                                         \
    for (int j = 0; j < 4; ++j) {                                             \
        __builtin_amdgcn_global_load_lds(                                     \
            (const __attribute__((address_space(1))) void*)                  \
                (gsrc + (j * 16384 + tid * 16)),                              \
            (__attribute__((address_space(3))) void*)(lbase + j * 16384),    \
            16, 0, 0);                                                        \
    }                                                                         \
    if (tid < PCELLS - 4096) {  /* tail cells 4096..4355 */                   \
        __builtin_amdgcn_global_load_lds(                                     \
            (const __attribute__((address_space(1))) void*)                  \
                (gsrc + (65536 + tid * 16)),                                  \
            (__attribute__((address_space(3))) void*)(lbase + 65536),        \
            16, 0, 0);                                                        \
    }                                                                         \
} while (0)

    float acc0[8] = {0}, acc1[8] = {0};

    // Preload ct rows for both phases (L2/L3-resident, once per kernel)
    const float2 ct1a = cb[t1 * HWn + px0], ct1b = cb[t1 * HWn + px1];
    const float2 ct2a = cb[t2 * HWn + px0], ct2b = cb[t2 * HWn + px1];

    // Coords for iter 0 (phase 1, k=0)
    PxCoord pcA = px_coord(ct1a, cb[px0], bx0, by0);
    PxCoord pcB = px_coord(ct1b, cb[px1], bx1, by1);
    // ck prefetch for iter 1 (k=1; t1>=16 so always phase 1)
    float2 ckpa = cb[HWn + px0], ckpb = cb[HWn + px1];

    STAGE(0, 0);                                // prologue: frame 0 -> buf0

    for (int i = 0; i < 33; ++i) {
        const int k = (i <= t1) ? i : i - t1 - 1;
        const int t = (i <= t1) ? t1 : t2;

        // barrier drains vmcnt(0): STAGE(i) complete; buf^1 readers done
        __syncthreads();
        if (i < 32) {                           // issue next DMA now; it
            const int kn = (i + 1 <= t1) ? (i + 1) : (i - t1);
            STAGE(kn, (i + 1) & 1);             // drains at NEXT barrier
        }

        // ---- issue gathers for iter i (addresses precomputed last iter)
        const PxCoord cA = pcA, cB = pcB;       // save before overwrite
        const uint4* fr = (const uint4*)(smem + (i & 1) * CHUNK_B);
        const uint4 a00 = fr[cA.off],      a10 = fr[cA.off + 1];
        const uint4 a01 = fr[cA.off + PW], a11 = fr[cA.off + PW + 1];
        const uint4 b00 = fr[cB.off],      b10 = fr[cB.off + 1];
        const uint4 b01 = fr[cB.off + PW], b11 = fr[cB.off + PW + 1];

        // ---- coords for iter i+1: independent VALU under ds_read latency
        if (i < 32) {
            const bool p2 = (i + 1 > t1);
            pcA = px_coord(p2 ? ct2a : ct1a, ckpa, bx0, by0);
            pcB = px_coord(p2 ? ct2b : ct1b, ckpb, bx1, by1);
            // prefetch ck for iter i+2 (clamped; harmless re-read at tail)
            const int j2 = (i + 2 <= 32) ? (i + 2) : 32;
            const int k2 = (j2 <= t1) ? j2 : j2 - t1 - 1;
            ckpa = cb[k2 * HWn + px0];
            ckpb = cb[k2 * HWn + px1];
        }

        // ---- MACs for iter i (64x v_fma_mix_f32)
        mac8(acc0, a00, cA.w00); mac8(acc0, a10, cA.w10);
        mac8(acc0, a01, cA.w01); mac8(acc0, a11, cA.w11);
        mac8(acc1, b00, cB.w00); mac8(acc1, b10, cB.w10);
        mac8(acc1, b01, cB.w01); mac8(acc1, b11, cB.w11);

        if (k == t) {                           // phase end: write + reset
            float* op = out + ((size_t)(b * LN + t) * CN + chh * 8) * HWn;
#pragma unroll
            for (int c = 0; c < 8; ++c) {
                op[c * HWn + px0] = acc0[c];
                op[c * HWn + px1] = acc1[c];
                acc0[c] = 0.f; acc1[c] = 0.f;
            }
        }
    }
#undef STAGE
}

// ---------------------------------------------------------------------------
// Fallback (ws too small / attr fails): direct fp32 gather (proven R1 kernel).
// ---------------------------------------------------------------------------
__global__ __launch_bounds__(256) void gsps_slow(
        const float* __restrict__ flows,
        const float* __restrict__ img,
        float* __restrict__ out) {
    const int bi = blockIdx.x;
    const int tile = bi & 15;
    const int rest = bi >> 4;
    const int t = 31 - (rest & 31);
    const int b = rest >> 5;
    const int p = (tile << 8) + threadIdx.x;
    const int h = p >> 6, w = p & 63;
    const float base_x = ((float)w + 0.5f) * 0.03125f - 1.0f;
    const float base_y = ((float)h + 0.5f) * 0.03125f - 1.0f;
    const float* fl = flows + (size_t)b * (LN * 2 * HWn) + p;

    float ctx = 0.f, cty = 0.f;
    for (int j = 0; j <= t; ++j) { ctx += fl[(2*j)*HWn]; cty += fl[(2*j+1)*HWn]; }

    float acc[16];
#pragma unroll
    for (int c = 0; c < 16; ++c) acc[c] = 0.f;

    float ckx = 0.f, cky = 0.f;
    for (int k = 0; k <= t; ++k) {
        ckx += fl[(2*k)*HWn]; cky += fl[(2*k+1)*HWn];
        float vx = (base_x + (ctx - ckx)) + 1.0f;
        float vy = (base_y + (cty - cky)) + 1.0f;
        float mx = vx - 2.0f * floorf(vx * 0.5f);
        float my = vy - 2.0f * floorf(vy * 0.5f);
        const float ix = ((mx - 1.0f) + 1.0f) * 32.0f - 0.5f;
        const float iy = ((my - 1.0f) + 1.0f) * 32.0f - 0.5f;
        const float x0f = floorf(ix), y0f = floorf(iy);
        const int x0 = (int)x0f, y0 = (int)y0f;
        const float wx1 = ix - x0f, wy1 = iy - y0f;
        const float wx0 = 1.0f - wx1, wy0 = 1.0f - wy1;
        const int x1 = x0 + 1, y1 = y0 + 1;
        const float fx0 = (x0 >= 0) ? 1.0f : 0.0f;
        const float fx1 = (x1 <= 63) ? 1.0f : 0.0f;
        const float fy0 = (y0 >= 0) ? 1.0f : 0.0f;
        const float fy1 = (y1 <= 63) ? 1.0f : 0.0f;
        const int x0c = (x0 < 0) ? 0 : x0, x1c = (x1 > 63) ? 63 : x1;
        const int y0c = (y0 < 0) ? 0 : y0, y1c = (y1 > 63) ? 63 : y1;
        const float w00 = (wx0*wy0)*(fx0*fy0), w10 = (wx1*wy0)*(fx1*fy0);
        const float w01 = (wx0*wy1)*(fx0*fy1), w11 = (wx1*wy1)*(fx1*fy1);
        const float* frm = img + (size_t)(b * LN + k) * FRAME;
        const int i00 = (y0c<<6)+x0c, i10 = (y0c<<6)+x1c;
        const int i01 = (y1c<<6)+x0c, i11 = (y1c<<6)+x1c;
#pragma unroll
        for (int c = 0; c < 16; ++c) {
            const float* pl = frm + c * HWn;
            acc[c] += ((w00*pl[i00] + w10*pl[i10]) + w01*pl[i01]) + w11*pl[i11];
        }
    }
    float* op = out + (size_t)(b * LN + t) * FRAME + p;
#pragma unroll
    for (int c = 0; c < 16; ++c) op[c * HWn] = acc[c];
}

extern "C" void kernel_launch(void* const* d_in, const int* in_sizes, int n_in,
                              void* d_out, int out_size, void* d_ws, size_t ws_size,
                              hipStream_t stream) {
    const float* flows  = (const float*)d_in[0];   // [4,32,2,64,64] f32
    const float* images = (const float*)d_in[1];   // [4,32,16,64,64] f32
    float* out = (float*)d_out;                    // [4,32,16,64,64] f32

    bool fast = (ws_size >= TIMG_BYTES + CUM_BYTES);
    if (fast) {
        hipError_t e = hipFuncSetAttribute(
            reinterpret_cast<const void*>(&gsps_lds),
            hipFuncAttributeMaxDynamicSharedMemorySize, 2 * CHUNK_B);
        if (e != hipSuccess) fast = false;
    }
    if (fast) {
        float4* timg = (float4*)d_ws;
        float2* cumw = (float2*)((char*)d_ws + TIMG_BYTES);
        prep_pad<<<BN * LN * 2, 1024, 0, stream>>>(images, timg);
        prep_cum<<<BN * 16, 256, 0, stream>>>(flows, cumw);
        gsps_lds<<<256, 1024, 2 * CHUNK_B, stream>>>(
            cumw, (const char*)timg, out);
    } else {
        gsps_slow<<<BN * LN * 16, 256, 0, stream>>>(flows, images, out);
    }
}

// Round 15
// 87.780 us; speedup vs baseline: 1.0041x; 1.0041x over previous
//
#include <hip/hip_runtime.h>

// GridSamplePScan: out[b,t,c] = sum_{k<=t} bilinear(images[b,k,c], wrap(base + cum_t - cum_k))
// B=4, L=32, C=16, H=W=64, fp32 in/out.
//
// R13 = R12 (63.1us, proven) + cross-iteration software pipeline:
//   R12 iter = coords(VALU) -> gathers(LDS) -> MACs(VALU) serialized by data
//   dependence, all waves in lockstep -> pipes SUM (4590cy = 1930V + 2550L).
//   Coords for iter i+1 depend only on cum (global, prefetched), NOT on the
//   staged frame -> precompute them during iter i's gather window:
//     barrier -> issue gathers(i) [addrs ready] -> STAGE(i+1) ->
//     coords(i+1) VALU under ds_read latency -> MACs(i)
//   ck loads prefetched 2 iters ahead; ct rows for both phases preloaded.
//   Math bit-identical to R12 (absmax 0.0625).

constexpr int BN = 4, LN = 32, CN = 16, HWn = 4096;
constexpr int FRAME = CN * HWn;
constexpr int PW = 66, PCELLS = PW * PW;                       // 4356 cells
constexpr int CHUNK_B = PCELLS * 16;                           // 69696 B
constexpr size_t TIMG_BYTES = (size_t)BN * LN * 2 * CHUNK_B;   // ~17.8 MB
constexpr size_t CUM_BYTES  = (size_t)BN * LN * HWn * 2 * 4;   // 4 MB

// ---------------------------------------------------------------------------
// images fp32 [B,L,C,H,W] -> fp16 padded [B*L][chh(2)][66][66][8ch] 16B cells.
// ---------------------------------------------------------------------------
__global__ __launch_bounds__(1024) void prep_pad(
        const float* __restrict__ img, float4* __restrict__ timg) {
    const int f = blockIdx.x >> 1, g = blockIdx.x & 1;         // frame, chhalf
    const float* src = img + (size_t)f * FRAME + g * (8 * HWn);
    float4* dst = timg + (size_t)blockIdx.x * PCELLS;
    for (int q = threadIdx.x; q < PCELLS; q += 1024) {
        const int y = q / PW, x = q - y * PW;
        union { float4 f4; _Float16 h[8]; } cell;
        if (y >= 1 && y <= 64 && x >= 1 && x <= 64) {
            const int p = ((y - 1) << 6) + (x - 1);
#pragma unroll
            for (int c = 0; c < 8; ++c)
                cell.h[c] = (_Float16)src[c * HWn + p];        // coalesced
        } else {
            cell.f4 = make_float4(0.f, 0.f, 0.f, 0.f);         // zero pad
        }
        dst[q] = cell.f4;
    }
}

// ---------------------------------------------------------------------------
// cumsum(flows) * 0.5 (exact scaling of the ROUNDED cumsum) -> [B*L][4096]
// ---------------------------------------------------------------------------
__global__ __launch_bounds__(256) void prep_cum(
        const float* __restrict__ flows, float2* __restrict__ cum) {
    const int b = blockIdx.x >> 4;
    const int p = ((blockIdx.x & 15) << 8) + threadIdx.x;
    const float* fl = flows + (size_t)b * (LN * 2 * HWn) + p;
    float cx = 0.f, cy = 0.f;
    for (int l = 0; l < LN; ++l) {              // ascending == jnp.cumsum
        cx += fl[(2 * l) * HWn];
        cy += fl[(2 * l + 1) * HWn];
        cum[(size_t)(b * LN + l) * HWn + p] =
            make_float2(cx * 0.5f, cy * 0.5f);  // exact *0.5
    }
}

// ---------------------------------------------------------------------------
// Guaranteed v_fma_mix_f32: acc += (float)f16(lo/hi of g) * w  (f32 fma)
// ---------------------------------------------------------------------------
__device__ __forceinline__ void mix_lo(float& acc, unsigned g, float w) {
    asm("v_fma_mix_f32 %0, %1, %2, %0 op_sel_hi:[1,0,0]"
        : "+v"(acc) : "v"(g), "v"(w));
}
__device__ __forceinline__ void mix_hi(float& acc, unsigned g, float w) {
    asm("v_fma_mix_f32 %0, %1, %2, %0 op_sel:[1,0,0] op_sel_hi:[1,0,0]"
        : "+v"(acc) : "v"(g), "v"(w));
}
__device__ __forceinline__ void mac8(float* __restrict__ acc, uint4 g, float w) {
    mix_lo(acc[0], g.x, w); mix_hi(acc[1], g.x, w);
    mix_lo(acc[2], g.y, w); mix_hi(acc[3], g.y, w);
    mix_lo(acc[4], g.z, w); mix_hi(acc[5], g.z, w);
    mix_lo(acc[6], g.w, w); mix_hi(acc[7], g.w, w);
}

// ---------------------------------------------------------------------------
// Coordinate/weight precompute (VALU only; no LDS dependence).
// ux = (bxh + dh) + 0.5 : reference association, halved (R12 proof).
// ---------------------------------------------------------------------------
struct PxCoord { int off; float w00, w10, w01, w11; };

__device__ __forceinline__ PxCoord px_coord(float2 ct, float2 ck,
                                            float bxh, float byh) {
    PxCoord r;
    const float ux = (bxh + (ct.x - ck.x)) + 0.5f;  // ref add order, halved
    const float uy = (byh + (ct.y - ck.y)) + 0.5f;
    const float fx = ux - floorf(ux);               // [0,1)
    const float fy = uy - floorf(uy);
    const float ixp = fmaf(fx, 64.0f, 0.5f);        // [0.5, 64.5)
    const float iyp = fmaf(fy, 64.0f, 0.5f);
    const float xf = floorf(ixp), yf = floorf(iyp);
    const float wx1 = ixp - xf, wy1 = iyp - yf;
    const float wx0 = 1.0f - wx1, wy0 = 1.0f - wy1;
    r.w00 = wx0 * wy0; r.w10 = wx1 * wy0;
    r.w01 = wx0 * wy1; r.w11 = wx1 * wy1;
    r.off = (int)yf * PW + (int)xf;                 // cell index, [0,64]^2
    return r;
}

// ---------------------------------------------------------------------------
// 256 blocks x 1024 thr (1/CU). Block = (b, pxhalf, pair, chh); thread: 2 px,
// 8 ch, 2 t-phases (triangle-paired: 33 uniform k-iters). R7 schedule +
// cross-iter coord pipeline.
// ---------------------------------------------------------------------------
__global__ __launch_bounds__(1024, 4) void gsps_lds(
        const float2* __restrict__ cum,
        const char* __restrict__ timg,
        float* __restrict__ out) {
    extern __shared__ char smem[];              // 2 x 69696 B double buffer
    const int bid = blockIdx.x;                 // 256 blocks
    const int xs  = bid & 7;                    // XCD slot
    const int b   = xs >> 1;                    // batch pinned to XCD pair
    const int pxh = xs & 1;
    const int seq = bid >> 3;
    const int pair = seq & 15;
    const int chh  = seq >> 4;
    const int tid  = threadIdx.x;
    const int t1 = 31 - pair;                   // heavy phase t  (>=16)
    const int t2 = pair;                        // light phase t

    const int px0 = (pxh << 11) + tid;
    const int px1 = px0 + 1024;
    // bxh = base_x/2 = (w+0.5)*2^-6 - 0.5   (both terms exact, diff exact)
    const float bx0 = ((float)(px0 & 63) + 0.5f) * 0.015625f - 0.5f;
    const float by0 = ((float)(px0 >> 6) + 0.5f) * 0.015625f - 0.5f;
    const float bx1 = ((float)(px1 & 63) + 0.5f) * 0.015625f - 0.5f;
    const float by1 = ((float)(px1 >> 6) + 0.5f) * 0.015625f - 0.5f;

    const float2* cb = cum + (size_t)b * (LN * HWn);
    const size_t chunk0 = ((size_t)b * LN * 2 + chh) * CHUNK_B;
    const unsigned wbase = (unsigned)(tid & ~63) << 4;   // wave-uniform

#define STAGE(KK, BUF) do {                                                   \
    const char* gsrc = timg + chunk0 + (size_t)(KK) * (2 * CHUNK_B);          \
    char* lbase = smem + (BUF) * CHUNK_B + wbase;                             \
    _Pragma("unroll")                                                         \
    for (int j = 0; j < 4; ++j) {                                             \
        __builtin_amdgcn_global_load_lds(                                     \
            (const __attribute__((address_space(1))) void*)                  \
                (gsrc + (j * 16384 + tid * 16)),                              \
            (__attribute__((address_space(3))) void*)(lbase + j * 16384),    \
            16, 0, 0);                                                        \
    }                                                                         \
    if (tid < PCELLS - 4096) {  /* tail cells 4096..4355 */                   \
        __builtin_amdgcn_global_load_lds(                                     \
            (const __attribute__((address_space(1))) void*)                  \
                (gsrc + (65536 + tid * 16)),                                  \
            (__attribute__((address_space(3))) void*)(lbase + 65536),        \
            16, 0, 0);                                                        \
    }                                                                         \
} while (0)

    float acc0[8] = {0}, acc1[8] = {0};

    // Preload ct rows for both phases (L2/L3-resident, once per kernel)
    const float2 ct1a = cb[t1 * HWn + px0], ct1b = cb[t1 * HWn + px1];
    const float2 ct2a = cb[t2 * HWn + px0], ct2b = cb[t2 * HWn + px1];

    // Coords for iter 0 (phase 1, k=0)
    PxCoord pcA = px_coord(ct1a, cb[px0], bx0, by0);
    PxCoord pcB = px_coord(ct1b, cb[px1], bx1, by1);
    // ck prefetch for iter 1 (k=1; t1>=16 so always phase 1)
    float2 ckpa = cb[HWn + px0], ckpb = cb[HWn + px1];

    STAGE(0, 0);                                // prologue: frame 0 -> buf0

    for (int i = 0; i < 33; ++i) {
        const int k = (i <= t1) ? i : i - t1 - 1;
        const int t = (i <= t1) ? t1 : t2;

        // barrier drains vmcnt(0): STAGE(i) complete; buf^1 readers done
        __syncthreads();
        if (i < 32) {                           // issue next DMA now; it
            const int kn = (i + 1 <= t1) ? (i + 1) : (i - t1);
            STAGE(kn, (i + 1) & 1);             // drains at NEXT barrier
        }

        // ---- issue gathers for iter i (addresses precomputed last iter)
        const PxCoord cA = pcA, cB = pcB;       // save before overwrite
        const uint4* fr = (const uint4*)(smem + (i & 1) * CHUNK_B);
        const uint4 a00 = fr[cA.off],      a10 = fr[cA.off + 1];
        const uint4 a01 = fr[cA.off + PW], a11 = fr[cA.off + PW + 1];
        const uint4 b00 = fr[cB.off],      b10 = fr[cB.off + 1];
        const uint4 b01 = fr[cB.off + PW], b11 = fr[cB.off + PW + 1];

        // ---- coords for iter i+1: independent VALU under ds_read latency
        if (i < 32) {
            const bool p2 = (i + 1 > t1);
            pcA = px_coord(p2 ? ct2a : ct1a, ckpa, bx0, by0);
            pcB = px_coord(p2 ? ct2b : ct1b, ckpb, bx1, by1);
            // prefetch ck for iter i+2 (clamped; harmless re-read at tail)
            const int j2 = (i + 2 <= 32) ? (i + 2) : 32;
            const int k2 = (j2 <= t1) ? j2 : j2 - t1 - 1;
            ckpa = cb[k2 * HWn + px0];
            ckpb = cb[k2 * HWn + px1];
        }

        // ---- MACs for iter i (64x v_fma_mix_f32)
        mac8(acc0, a00, cA.w00); mac8(acc0, a10, cA.w10);
        mac8(acc0, a01, cA.w01); mac8(acc0, a11, cA.w11);
        mac8(acc1, b00, cB.w00); mac8(acc1, b10, cB.w10);
        mac8(acc1, b01, cB.w01); mac8(acc1, b11, cB.w11);

        if (k == t) {                           // phase end: write + reset
            float* op = out + ((size_t)(b * LN + t) * CN + chh * 8) * HWn;
#pragma unroll
            for (int c = 0; c < 8; ++c) {
                op[c * HWn + px0] = acc0[c];
                op[c * HWn + px1] = acc1[c];
                acc0[c] = 0.f; acc1[c] = 0.f;
            }
        }
    }
#undef STAGE
}

// ---------------------------------------------------------------------------
// Fallback (ws too small / attr fails): direct fp32 gather (proven R1 kernel).
// ---------------------------------------------------------------------------
__global__ __launch_bounds__(256) void gsps_slow(
        const float* __restrict__ flows,
        const float* __restrict__ img,
        float* __restrict__ out) {
    const int bi = blockIdx.x;
    const int tile = bi & 15;
    const int rest = bi >> 4;
    const int t = 31 - (rest & 31);
    const int b = rest >> 5;
    const int p = (tile << 8) + threadIdx.x;
    const int h = p >> 6, w = p & 63;
    const float base_x = ((float)w + 0.5f) * 0.03125f - 1.0f;
    const float base_y = ((float)h + 0.5f) * 0.03125f - 1.0f;
    const float* fl = flows + (size_t)b * (LN * 2 * HWn) + p;

    float ctx = 0.f, cty = 0.f;
    for (int j = 0; j <= t; ++j) { ctx += fl[(2*j)*HWn]; cty += fl[(2*j+1)*HWn]; }

    float acc[16];
#pragma unroll
    for (int c = 0; c < 16; ++c) acc[c] = 0.f;

    float ckx = 0.f, cky = 0.f;
    for (int k = 0; k <= t; ++k) {
        ckx += fl[(2*k)*HWn]; cky += fl[(2*k+1)*HWn];
        float vx = (base_x + (ctx - ckx)) + 1.0f;
        float vy = (base_y + (cty - cky)) + 1.0f;
        float mx = vx - 2.0f * floorf(vx * 0.5f);
        float my = vy - 2.0f * floorf(vy * 0.5f);
        const float ix = ((mx - 1.0f) + 1.0f) * 32.0f - 0.5f;
        const float iy = ((my - 1.0f) + 1.0f) * 32.0f - 0.5f;
        const float x0f = floorf(ix), y0f = floorf(iy);
        const int x0 = (int)x0f, y0 = (int)y0f;
        const float wx1 = ix - x0f, wy1 = iy - y0f;
        const float wx0 = 1.0f - wx1, wy0 = 1.0f - wy1;
        const int x1 = x0 + 1, y1 = y0 + 1;
        const float fx0 = (x0 >= 0) ? 1.0f : 0.0f;
        const float fx1 = (x1 <= 63) ? 1.0f : 0.0f;
        const float fy0 = (y0 >= 0) ? 1.0f : 0.0f;
        const float fy1 = (y1 <= 63) ? 1.0f : 0.0f;
        const int x0c = (x0 < 0) ? 0 : x0, x1c = (x1 > 63) ? 63 : x1;
        const int y0c = (y0 < 0) ? 0 : y0, y1c = (y1 > 63) ? 63 : y1;
        const float w00 = (wx0*wy0)*(fx0*fy0), w10 = (wx1*wy0)*(fx1*fy0);
        const float w01 = (wx0*wy1)*(fx0*fy1), w11 = (wx1*wy1)*(fx1*fy1);
        const float* frm = img + (size_t)(b * LN + k) * FRAME;
        const int i00 = (y0c<<6)+x0c, i10 = (y0c<<6)+x1c;
        const int i01 = (y1c<<6)+x0c, i11 = (y1c<<6)+x1c;
#pragma unroll
        for (int c = 0; c < 16; ++c) {
            const float* pl = frm + c * HWn;
            acc[c] += ((w00*pl[i00] + w10*pl[i10]) + w01*pl[i01]) + w11*pl[i11];
        }
    }
    float* op = out + (size_t)(b * LN + t) * FRAME + p;
#pragma unroll
    for (int c = 0; c < 16; ++c) op[c * HWn] = acc[c];
}

extern "C" void kernel_launch(void* const* d_in, const int* in_sizes, int n_in,
                              void* d_out, int out_size, void* d_ws, size_t ws_size,
                              hipStream_t stream) {
    const float* flows  = (const float*)d_in[0];   // [4,32,2,64,64] f32
    const float* images = (const float*)d_in[1];   // [4,32,16,64,64] f32
    float* out = (float*)d_out;                    // [4,32,16,64,64] f32

    bool fast = (ws_size >= TIMG_BYTES + CUM_BYTES);
    if (fast) {
        hipError_t e = hipFuncSetAttribute(
            reinterpret_cast<const void*>(&gsps_lds),
            hipFuncAttributeMaxDynamicSharedMemorySize, 2 * CHUNK_B);
        if (e != hipSuccess) fast = false;
    }
    if (fast) {
        float4* timg = (float4*)d_ws;
        float2* cumw = (float2*)((char*)d_ws + TIMG_BYTES);
        prep_pad<<<BN * LN * 2, 1024, 0, stream>>>(images, timg);
        prep_cum<<<BN * 16, 256, 0, stream>>>(flows, cumw);
        gsps_lds<<<256, 1024, 2 * CHUNK_B, stream>>>(
            cumw, (const char*)timg, out);
    } else {
        gsps_slow<<<BN * LN * 16, 256, 0, stream>>>(flows, images, out);
    }
}

// Round 16
// 84.577 us; speedup vs baseline: 1.0421x; 1.0379x over previous
//
#include <hip/hip_runtime.h>

// GridSamplePScan: out[b,t,c] = sum_{k<=t} bilinear(images[b,k,c], wrap(base + cum_t - cum_k))
// B=4, L=32, C=16, H=W=64, fp32 in/out.
//
// R15 = R12 body (proven 63.1us, absmax 0.0625) + XCD remap.
//   R13 lesson: pipes are in strict SUM regime; coord pipelining added VALU
//   for zero overlap -> reverted. Budget gap ~1200cy/iter = DMA drain stall:
//   old mapping put (b,pxh) in XCD bits -> each XCD pulled BOTH chh chunk
//   sets = 4.46MB > 4MiB L2 -> L3 thrash on every STAGE. New mapping puts
//   (b,chh) in XCD bits: 2.23MB per XCD (L2-fits) and pxh-sibling blocks on
//   the SAME XCD stage the SAME chunks in the same order -> halved L2 pulls.

constexpr int BN = 4, LN = 32, CN = 16, HWn = 4096;
constexpr int FRAME = CN * HWn;
constexpr int PW = 66, PCELLS = PW * PW;                       // 4356 cells
constexpr int CHUNK_B = PCELLS * 16;                           // 69696 B
constexpr size_t TIMG_BYTES = (size_t)BN * LN * 2 * CHUNK_B;   // ~17.8 MB
constexpr size_t CUM_BYTES  = (size_t)BN * LN * HWn * 2 * 4;   // 4 MB

// ---------------------------------------------------------------------------
// images fp32 [B,L,C,H,W] -> fp16 padded [B*L][chh(2)][66][66][8ch] 16B cells.
// ---------------------------------------------------------------------------
__global__ __launch_bounds__(1024) void prep_pad(
        const float* __restrict__ img, float4* __restrict__ timg) {
    const int f = blockIdx.x >> 1, g = blockIdx.x & 1;         // frame, chhalf
    const float* src = img + (size_t)f * FRAME + g * (8 * HWn);
    float4* dst = timg + (size_t)blockIdx.x * PCELLS;
    for (int q = threadIdx.x; q < PCELLS; q += 1024) {
        const int y = q / PW, x = q - y * PW;
        union { float4 f4; _Float16 h[8]; } cell;
        if (y >= 1 && y <= 64 && x >= 1 && x <= 64) {
            const int p = ((y - 1) << 6) + (x - 1);
#pragma unroll
            for (int c = 0; c < 8; ++c)
                cell.h[c] = (_Float16)src[c * HWn + p];        // coalesced
        } else {
            cell.f4 = make_float4(0.f, 0.f, 0.f, 0.f);         // zero pad
        }
        dst[q] = cell.f4;
    }
}

// ---------------------------------------------------------------------------
// cumsum(flows) * 0.5 (exact scaling of the ROUNDED cumsum) -> [B*L][4096]
// ---------------------------------------------------------------------------
__global__ __launch_bounds__(256) void prep_cum(
        const float* __restrict__ flows, float2* __restrict__ cum) {
    const int b = blockIdx.x >> 4;
    const int p = ((blockIdx.x & 15) << 8) + threadIdx.x;
    const float* fl = flows + (size_t)b * (LN * 2 * HWn) + p;
    float cx = 0.f, cy = 0.f;
    for (int l = 0; l < LN; ++l) {              // ascending == jnp.cumsum
        cx += fl[(2 * l) * HWn];
        cy += fl[(2 * l + 1) * HWn];
        cum[(size_t)(b * LN + l) * HWn + p] =
            make_float2(cx * 0.5f, cy * 0.5f);  // exact *0.5
    }
}

// ---------------------------------------------------------------------------
// Guaranteed v_fma_mix_f32: acc += (float)f16(lo/hi of g) * w  (f32 fma)
// ---------------------------------------------------------------------------
__device__ __forceinline__ void mix_lo(float& acc, unsigned g, float w) {
    asm("v_fma_mix_f32 %0, %1, %2, %0 op_sel_hi:[1,0,0]"
        : "+v"(acc) : "v"(g), "v"(w));
}
__device__ __forceinline__ void mix_hi(float& acc, unsigned g, float w) {
    asm("v_fma_mix_f32 %0, %1, %2, %0 op_sel:[1,0,0] op_sel_hi:[1,0,0]"
        : "+v"(acc) : "v"(g), "v"(w));
}
__device__ __forceinline__ void mac8(float* __restrict__ acc, uint4 g, float w) {
    mix_lo(acc[0], g.x, w); mix_hi(acc[1], g.x, w);
    mix_lo(acc[2], g.y, w); mix_hi(acc[3], g.y, w);
    mix_lo(acc[4], g.z, w); mix_hi(acc[5], g.z, w);
    mix_lo(acc[6], g.w, w); mix_hi(acc[7], g.w, w);
}

// ---------------------------------------------------------------------------
// Bilinear from padded LDS frame. No masks: pad cells are zero.
// ux = (bxh + dh) + 0.5 : reference association, halved (R12 proof):
//   bxh = base_x*0.5, cum stored *0.5 -> fl(bxh+dh) = fl(base+rel)/2,
//   ux = fl(.+0.5) = fl(fl(base+rel)+1)/2; fract/ixp scalings exact. QED.
// ---------------------------------------------------------------------------
__device__ __forceinline__ void px_step(const uint4* __restrict__ fr,
                                        float2 ct, float2 ck,
                                        float bxh, float byh,
                                        float* __restrict__ acc) {
    const float ux = (bxh + (ct.x - ck.x)) + 0.5f;  // ref add order, halved
    const float uy = (byh + (ct.y - ck.y)) + 0.5f;
    const float fx = ux - floorf(ux);               // [0,1)
    const float fy = uy - floorf(uy);
    const float ixp = fmaf(fx, 64.0f, 0.5f);        // [0.5, 64.5)
    const float iyp = fmaf(fy, 64.0f, 0.5f);
    const float xf = floorf(ixp), yf = floorf(iyp);
    const int x0p = (int)xf, y0p = (int)yf;         // [0, 64]
    const float wx1 = ixp - xf, wy1 = iyp - yf;
    const float wx0 = 1.0f - wx1, wy0 = 1.0f - wy1;
    const float w00 = wx0 * wy0, w10 = wx1 * wy0;
    const float w01 = wx0 * wy1, w11 = wx1 * wy1;
    const int i00 = y0p * PW + x0p;
    const uint4 g00 = fr[i00];                      // ds_read_b128
    const uint4 g10 = fr[i00 + 1];
    const uint4 g01 = fr[i00 + PW];
    const uint4 g11 = fr[i00 + PW + 1];
    mac8(acc, g00, w00);                            // 32x v_fma_mix_f32
    mac8(acc, g10, w10);
    mac8(acc, g01, w01);
    mac8(acc, g11, w11);
}

// ---------------------------------------------------------------------------
// 256 blocks x 1024 thr (1/CU). Block = (b, chh | pair, pxh); thread: 2 px,
// 8 ch, 2 t-phases (triangle-paired: 33 uniform k-iters). R7/R12 schedule.
// XCD slot = (b, chh): per-XCD staging working set = 32 chunks = 2.23MB
// (L2-fits); pxh-siblings on the same XCD share every staged chunk.
// ---------------------------------------------------------------------------
__global__ __launch_bounds__(1024, 4) void gsps_lds(
        const float2* __restrict__ cum,
        const char* __restrict__ timg,
        float* __restrict__ out) {
    extern __shared__ char smem[];              // 2 x 69696 B double buffer
    const int bid = blockIdx.x;                 // 256 blocks
    const int xs  = bid & 7;                    // XCD slot
    const int b   = xs >> 1;                    // batch pinned to XCD pair
    const int chh = xs & 1;                     // chh pinned to ONE XCD
    const int seq = bid >> 3;
    const int pair = seq & 15;
    const int pxh  = seq >> 4;                  // pxh-siblings same XCD
    const int tid  = threadIdx.x;
    const int t1 = 31 - pair;                   // heavy phase t
    const int t2 = pair;                        // light phase t

    const int px0 = (pxh << 11) + tid;
    const int px1 = px0 + 1024;
    // bxh = base_x/2 = (w+0.5)*2^-6 - 0.5   (both terms exact, diff exact)
    const float bx0 = ((float)(px0 & 63) + 0.5f) * 0.015625f - 0.5f;
    const float by0 = ((float)(px0 >> 6) + 0.5f) * 0.015625f - 0.5f;
    const float bx1 = ((float)(px1 & 63) + 0.5f) * 0.015625f - 0.5f;
    const float by1 = ((float)(px1 >> 6) + 0.5f) * 0.015625f - 0.5f;

    const float2* cb = cum + (size_t)b * (LN * HWn);
    // chunk base for (b, k, chh): ((b*32 + k)*2 + chh) * CHUNK_B
    const size_t chunk0 = ((size_t)b * LN * 2 + chh) * CHUNK_B;
    const unsigned wbase = (unsigned)(tid & ~63) << 4;   // wave-uniform

    // LDS dest: wave-uniform base (+ HW lane*16); global src per-lane.
#define STAGE(KK, BUF) do {                                                   \
    const char* gsrc = timg + chunk0 + (size_t)(KK) * (2 * CHUNK_B);          \
    char* lbase = smem + (BUF) * CHUNK_B + wbase;                             \
    _Pragma("unroll")                                                         \
    for (int j = 0; j < 4; ++j) {                                             \
        __builtin_amdgcn_global_load_lds(                                     \
            (const __attribute__((address_space(1))) void*)                  \
                (gsrc + (j * 16384 + tid * 16)),                              \
            (__attribute__((address_space(3))) void*)(lbase + j * 16384),    \
            16, 0, 0);                                                        \
    }                                                                         \
    if (tid < PCELLS - 4096) {  /* tail cells 4096..4355 */                   \
        __builtin_amdgcn_global_load_lds(                                     \
            (const __attribute__((address_space(1))) void*)                  \
                (gsrc + (65536 + tid * 16)),                                  \
            (__attribute__((address_space(3))) void*)(lbase + 65536),        \
            16, 0, 0);                                                        \
    }                                                                         \
} while (0)

    float acc0[8] = {0}, acc1[8] = {0};
    float2 ct0 = make_float2(0.f, 0.f), ct1 = ct0;
    float2 ckp0 = cb[px0], ckp1 = cb[px1];      // ck prefetch for iter 0

    STAGE(0, 0);                                // prologue: frame 0 -> buf0

    for (int i = 0; i < 33; ++i) {
        const bool ph2 = (i > t1);
        const int k = ph2 ? (i - t1 - 1) : i;
        const int t = ph2 ? t2 : t1;

        // barrier drains vmcnt(0): STAGE(i) complete; buf^1 readers done
        __syncthreads();
        if (i < 32) {                           // issue next DMA now; it
            const int kn = (i + 1 > t1) ? (i - t1) : (i + 1);
            STAGE(kn, (i + 1) & 1);             // drains at NEXT barrier
        }

        const float2 ck0 = ckp0, ck1 = ckp1;
        if (i < 32) {                           // prefetch next ck pair
            const int kn = (i + 1 > t1) ? (i - t1) : (i + 1);
            ckp0 = cb[kn * HWn + px0];
            ckp1 = cb[kn * HWn + px1];
        }
        if (k == 0) {                           // phase start
            ct0 = cb[t * HWn + px0];
            ct1 = cb[t * HWn + px1];
#pragma unroll
            for (int c = 0; c < 8; ++c) { acc0[c] = 0.f; acc1[c] = 0.f; }
        }
        const uint4* fr = (const uint4*)(smem + (i & 1) * CHUNK_B);
        px_step(fr, ct0, ck0, bx0, by0, acc0);
        px_step(fr, ct1, ck1, bx1, by1, acc1);

        if (k == t) {                           // phase end: write out
            float* op = out + ((size_t)(b * LN + t) * CN + chh * 8) * HWn;
#pragma unroll
            for (int c = 0; c < 8; ++c) {
                op[c * HWn + px0] = acc0[c];
                op[c * HWn + px1] = acc1[c];
            }
        }
    }
#undef STAGE
}

// ---------------------------------------------------------------------------
// Fallback (ws too small / attr fails): direct fp32 gather (proven R1 kernel).
// ---------------------------------------------------------------------------
__global__ __launch_bounds__(256) void gsps_slow(
        const float* __restrict__ flows,
        const float* __restrict__ img,
        float* __restrict__ out) {
    const int bi = blockIdx.x;
    const int tile = bi & 15;
    const int rest = bi >> 4;
    const int t = 31 - (rest & 31);
    const int b = rest >> 5;
    const int p = (tile << 8) + threadIdx.x;
    const int h = p >> 6, w = p & 63;
    const float base_x = ((float)w + 0.5f) * 0.03125f - 1.0f;
    const float base_y = ((float)h + 0.5f) * 0.03125f - 1.0f;
    const float* fl = flows + (size_t)b * (LN * 2 * HWn) + p;

    float ctx = 0.f, cty = 0.f;
    for (int j = 0; j <= t; ++j) { ctx += fl[(2*j)*HWn]; cty += fl[(2*j+1)*HWn]; }

    float acc[16];
#pragma unroll
    for (int c = 0; c < 16; ++c) acc[c] = 0.f;

    float ckx = 0.f, cky = 0.f;
    for (int k = 0; k <= t; ++k) {
        ckx += fl[(2*k)*HWn]; cky += fl[(2*k+1)*HWn];
        float vx = (base_x + (ctx - ckx)) + 1.0f;
        float vy = (base_y + (cty - cky)) + 1.0f;
        float mx = vx - 2.0f * floorf(vx * 0.5f);
        float my = vy - 2.0f * floorf(vy * 0.5f);
        const float ix = ((mx - 1.0f) + 1.0f) * 32.0f - 0.5f;
        const float iy = ((my - 1.0f) + 1.0f) * 32.0f - 0.5f;
        const float x0f = floorf(ix), y0f = floorf(iy);
        const int x0 = (int)x0f, y0 = (int)y0f;
        const float wx1 = ix - x0f, wy1 = iy - y0f;
        const float wx0 = 1.0f - wx1, wy0 = 1.0f - wy1;
        const int x1 = x0 + 1, y1 = y0 + 1;
        const float fx0 = (x0 >= 0) ? 1.0f : 0.0f;
        const float fx1 = (x1 <= 63) ? 1.0f : 0.0f;
        const float fy0 = (y0 >= 0) ? 1.0f : 0.0f;
        const float fy1 = (y1 <= 63) ? 1.0f : 0.0f;
        const int x0c = (x0 < 0) ? 0 : x0, x1c = (x1 > 63) ? 63 : x1;
        const int y0c = (y0 < 0) ? 0 : y0, y1c = (y1 > 63) ? 63 : y1;
        const float w00 = (wx0*wy0)*(fx0*fy0), w10 = (wx1*wy0)*(fx1*fy0);
        const float w01 = (wx0*wy1)*(fx0*fy1), w11 = (wx1*wy1)*(fx1*fy1);
        const float* frm = img + (size_t)(b * LN + k) * FRAME;
        const int i00 = (y0c<<6)+x0c, i10 = (y0c<<6)+x1c;
        const int i01 = (y1c<<6)+x0c, i11 = (y1c<<6)+x1c;
#pragma unroll
        for (int c = 0; c < 16; ++c) {
            const float* pl = frm + c * HWn;
            acc[c] += ((w00*pl[i00] + w10*pl[i10]) + w01*pl[i01]) + w11*pl[i11];
        }
    }
    float* op = out + (size_t)(b * LN + t) * FRAME + p;
#pragma unroll
    for (int c = 0; c < 16; ++c) op[c * HWn] = acc[c];
}

extern "C" void kernel_launch(void* const* d_in, const int* in_sizes, int n_in,
                              void* d_out, int out_size, void* d_ws, size_t ws_size,
                              hipStream_t stream) {
    const float* flows  = (const float*)d_in[0];   // [4,32,2,64,64] f32
    const float* images = (const float*)d_in[1];   // [4,32,16,64,64] f32
    float* out = (float*)d_out;                    // [4,32,16,64,64] f32

    bool fast = (ws_size >= TIMG_BYTES + CUM_BYTES);
    if (fast) {
        hipError_t e = hipFuncSetAttribute(
            reinterpret_cast<const void*>(&gsps_lds),
            hipFuncAttributeMaxDynamicSharedMemorySize, 2 * CHUNK_B);
        if (e != hipSuccess) fast = false;
    }
    if (fast) {
        float4* timg = (float4*)d_ws;
        float2* cumw = (float2*)((char*)d_ws + TIMG_BYTES);
        prep_pad<<<BN * LN * 2, 1024, 0, stream>>>(images, timg);
        prep_cum<<<BN * 16, 256, 0, stream>>>(flows, cumw);
        gsps_lds<<<256, 1024, 2 * CHUNK_B, stream>>>(
            cumw, (const char*)timg, out);
    } else {
        gsps_slow<<<BN * LN * 16, 256, 0, stream>>>(flows, images, out);
    }
}